// Round 3
// baseline (472.265 us; speedup 1.0000x reference)
//
#include <hip/hip_runtime.h>

// Problem: S=1024, B=32, D=1024.  All float tensors FP32; output FP32.
// out[i,b,:] = valid[b,i]/denom[i,b] * sum_j w[i,b,j] * PE[j,b,:]
//   w[i,b,j] = valid[b,j] / ((c_ib - j)^2 + 1e-3),  c_ib = sigmoid(x[i,b]·W+b0)*slen_b + (S-slen_b)
// Pipeline: prep (mask->valid/slen) -> mid v3 (rowk 2-rows/wave with up-front loads + v_rcp;
//           transpose v1 body pipelined 2 tiles/block; families interleaved bid&1)
//           -> batched bf16 MFMA GEMM (256^2 tile, counted-vmcnt pipeline).
// Denominator sums the bf16-ROUNDED weights so P-quantization error cancels in normalization.
// rcp note: v_rcp_f32 rel err ~2e-7 << bf16 quantization (4e-3); numerator and denominator
// use the SAME rounded bf16 weights, so consistency is preserved.

#define S_ 1024
#define B_ 32
#define D_ 1024

typedef unsigned short us;
typedef __attribute__((ext_vector_type(4))) unsigned short us4;
typedef __attribute__((ext_vector_type(4))) float f4;
typedef __attribute__((ext_vector_type(8))) short short8;

__device__ __forceinline__ float bf2f(us u){
  unsigned v = ((unsigned)u) << 16;
  float f;
  __builtin_memcpy(&f, &v, 4);
  return f;
}
__device__ __forceinline__ us f2bf(float f){
  unsigned v;
  __builtin_memcpy(&v, &f, 4);
  v = v + 0x7fffu + ((v >> 16) & 1u);   // RNE
  return (us)(v >> 16);
}

// async global->LDS, 16B per lane; lds ptr must be wave-uniform (dest = base + lane*16)
__device__ __forceinline__ void gll16(const void* g, void* l){
  __builtin_amdgcn_global_load_lds(
      (const __attribute__((address_space(1))) void*)g,
      (__attribute__((address_space(3))) void*)l,
      16, 0, 0);
}

// ---------------- kernel 1: mask -> valid_f, slen, ltok (bool storage autodetect) ----------
__global__ __launch_bounds__(256) void prep_k(const unsigned char* __restrict__ mask,
                                              float* __restrict__ valid,
                                              float* __restrict__ slen,
                                              float* __restrict__ ltok)
{
  const int b = blockIdx.x;
  const int t = threadIdx.x;
  __shared__ int flags[5];   // nonzero seen at byte%4==0..3, [4]=any byte>1
  __shared__ int red[256];
  if (t < 5) flags[t] = 0;
  __syncthreads();
  for (int k = 0; k < 32; ++k){
    int p = t * 32 + k;
    unsigned v = mask[p];
    if (v){
      atomicOr(&flags[p & 3], 1);
      if (v > 1u) atomicOr(&flags[4], 1);
    }
  }
  __syncthreads();
  int fmt;  // 0=u8, 1=i32, 2=bf16, 3=f32
  int any123 = flags[1] | flags[2] | flags[3];
  if (!flags[4]) fmt = any123 ? 0 : 1;
  else           fmt = (flags[0] | flags[1]) ? 2 : 3;

  int cnt = 0;
#pragma unroll
  for (int q = 0; q < 4; ++q){
    int j = t + q * 256;
    size_t idx = (size_t)b * S_ + j;
    unsigned mv;
    if (fmt == 0)      mv = mask[idx];
    else if (fmt == 1) mv = ((const unsigned int*)mask)[idx];
    else if (fmt == 2) mv = ((const unsigned short*)mask)[idx];
    else               mv = ((const unsigned int*)mask)[idx] & 0x7fffffffu;
    valid[idx] = mv ? 0.0f : 1.0f;
    cnt += mv ? 0 : 1;
  }
  red[t] = cnt;
  __syncthreads();
  for (int s = 128; s > 0; s >>= 1){
    if (t < s) red[t] += red[t + s];
    __syncthreads();
  }
  if (t == 0){
    float cn = (float)red[0];
    slen[b] = cn;
    ltok[b] = (float)S_ - cn;
  }
}

// ---------------- rowk: process one row given pre-loaded x regs ----------------------------
__device__ __forceinline__ void rowk_row(int row, const float4 xv[4],
                                         const float* __restrict__ Wp,
                                         const float* __restrict__ bp,
                                         const float* __restrict__ valid,
                                         const float* __restrict__ slen,
                                         const float* __restrict__ ltok,
                                         us* __restrict__ P,
                                         float* __restrict__ rs,
                                         float* __restrict__ c_arr)
{
  const int lane = threadIdx.x & 63;
  const int b = row & (B_ - 1);
  const int i = row >> 5;
  const float4* wr = (const float4*)Wp;

  float acc = 0.f;
#pragma unroll
  for (int q = 0; q < 4; ++q){
    float4 wv = wr[q * 64 + lane];          // L1-resident (same 4KB for all rows)
    acc += xv[q].x * wv.x + xv[q].y * wv.y + xv[q].z * wv.z + xv[q].w * wv.w;
  }
#pragma unroll
  for (int off = 32; off > 0; off >>= 1) acc += __shfl_xor(acc, off);

  float z   = acc + bp[0];
  float sig = 1.f / (1.f + expf(-z));
  float c   = sig * slen[b] + ltok[b];

  const float4* vr = (const float4*)(valid + (size_t)b * S_);
  us4* Pr = (us4*)(P + ((size_t)b * S_ + i) * S_);
  float wsum = 0.f;
#pragma unroll
  for (int q = 0; q < 4; ++q){
    int idx = q * 64 + lane;
    float4 vv = vr[idx];
    float j0 = (float)(idx * 4);
    float d0 = c - j0;
    float d1 = c - (j0 + 1.f);
    float d2 = c - (j0 + 2.f);
    float d3 = c - (j0 + 3.f);
    // v_rcp_f32: 1-instr reciprocal; error ~2e-7 rel, far below bf16 rounding below
    us p0 = f2bf(vv.x * __builtin_amdgcn_rcpf(d0 * d0 + 1e-3f));
    us p1 = f2bf(vv.y * __builtin_amdgcn_rcpf(d1 * d1 + 1e-3f));
    us p2 = f2bf(vv.z * __builtin_amdgcn_rcpf(d2 * d2 + 1e-3f));
    us p3 = f2bf(vv.w * __builtin_amdgcn_rcpf(d3 * d3 + 1e-3f));
    us4 pv; pv.x = p0; pv.y = p1; pv.z = p2; pv.w = p3;
    Pr[idx] = pv;
    wsum += bf2f(p0) + bf2f(p1) + bf2f(p2) + bf2f(p3);
  }
#pragma unroll
  for (int off = 32; off > 0; off >>= 1) wsum += __shfl_xor(wsum, off);

  if (lane == 0){
    float vi = valid[(size_t)b * S_ + i];
    rs[(size_t)b * S_ + i] = (vi != 0.f) ? (vi / wsum) : 0.f;   // keep exact div (1/row)
    c_arr[(size_t)b * S_ + i] = c;
  }
}

// ---------------- rowk: 2 rows/wave, both rows' x-loads issued up front --------------------
__device__ __forceinline__ void rowk_pipe(int g, const float* __restrict__ x,
                                          const float* __restrict__ Wp,
                                          const float* __restrict__ bp,
                                          const float* __restrict__ valid,
                                          const float* __restrict__ slen,
                                          const float* __restrict__ ltok,
                                          us* __restrict__ P,
                                          float* __restrict__ rs,
                                          float* __restrict__ c_arr)
{
  const int wid  = threadIdx.x >> 6;
  const int lane = threadIdx.x & 63;
  const int row0 = g * 8 + wid * 2;

  const float4* xr0 = (const float4*)(x + (size_t)row0 * D_);
  const float4* xr1 = (const float4*)(x + (size_t)(row0 + 1) * D_);
  float4 xa[4], xb[4];
#pragma unroll
  for (int q = 0; q < 4; ++q) xa[q] = xr0[q * 64 + lane];
#pragma unroll
  for (int q = 0; q < 4; ++q) xb[q] = xr1[q * 64 + lane];   // in flight during row0's chain

  rowk_row(row0,     xa, Wp, bp, valid, slen, ltok, P, rs, c_arr);
  rowk_row(row0 + 1, xb, Wp, bp, valid, slen, ltok, P, rs, c_arr);
}

// ---------------- PE transpose v1 body, regs pre-loaded ------------------------------------
// LDS tile us[64j][68] (pad breaks power-of-2); writes us4, reads scalar u16 x4 -> us4 stores.
__device__ __forceinline__ void transp_store(int j0, int d0, int b, const float4 v[4],
                                             us* __restrict__ Etr, us* tile)
{
  const int t  = threadIdx.x;
  const int rr = t >> 4, cc = t & 15;
#pragma unroll
  for (int q = 0; q < 4; ++q){
    int j = q * 16 + rr;
    us4 tv; tv.x = f2bf(v[q].x); tv.y = f2bf(v[q].y); tv.z = f2bf(v[q].z); tv.w = f2bf(v[q].w);
    *(us4*)&tile[j * 68 + cc * 4] = tv;
  }
  __syncthreads();
#pragma unroll
  for (int q = 0; q < 4; ++q){
    int d = q * 16 + rr;
    us4 o;
    o.x = tile[(cc * 4 + 0) * 68 + d];
    o.y = tile[(cc * 4 + 1) * 68 + d];
    o.z = tile[(cc * 4 + 2) * 68 + d];
    o.w = tile[(cc * 4 + 3) * 68 + d];
    *(us4*)(Etr + ((size_t)b * D_ + d0 + d) * S_ + j0 + cc * 4) = o;
  }
}

// 2 tiles per block; tile1's global reads issued before tile0's LDS/store phase.
__device__ __forceinline__ void transp_pipe(int g, const float* __restrict__ pe,
                                            us* __restrict__ Etr, us* tile)
{
  const int t  = threadIdx.x;
  const int rr = t >> 4, cc = t & 15;

  const int id0 = g * 2, id1 = g * 2 + 1;
  const int j00 = (id0 & 15) * 64,      j01 = (id1 & 15) * 64;
  const int d00 = ((id0 >> 4) & 15) * 64, d01 = ((id1 >> 4) & 15) * 64;
  const int b0  = id0 >> 8,             b1  = id1 >> 8;

  float4 va[4], vb[4];
#pragma unroll
  for (int q = 0; q < 4; ++q){
    int j = q * 16 + rr;
    va[q] = *(const float4*)(pe + ((size_t)(j00 + j) * B_ + b0) * D_ + d00 + cc * 4);
  }
#pragma unroll
  for (int q = 0; q < 4; ++q){
    int j = q * 16 + rr;
    vb[q] = *(const float4*)(pe + ((size_t)(j01 + j) * B_ + b1) * D_ + d01 + cc * 4);
  }

  transp_store(j00, d00, b0, va, Etr, tile);
  __syncthreads();                         // tile reuse hazard
  transp_store(j01, d01, b1, vb, Etr, tile);
}

// ---------------- kernel 2 (FUSED, INTERLEAVED): bid&1 -> rowk, else transpose -------------
__global__ __launch_bounds__(256) void mid_k(const float* __restrict__ x,
                                             const float* __restrict__ Wp,
                                             const float* __restrict__ bp,
                                             const float* __restrict__ valid,
                                             const float* __restrict__ slen,
                                             const float* __restrict__ ltok,
                                             us* __restrict__ P,
                                             float* __restrict__ rs,
                                             float* __restrict__ c_arr,
                                             const float* __restrict__ pe,
                                             us* __restrict__ Etr)
{
  __shared__ us tile[64 * 68];   // 8704 B
  const int bid = blockIdx.x;
  const int g = bid >> 1;
  if (bid & 1){
    rowk_pipe(g, x, Wp, bp, valid, slen, ltok, P, rs, c_arr);
  } else {
    transp_pipe(g, pe, Etr, tile);
  }
}

// ---------------- kernel 3: batched GEMM out = rowscale * (P @ E) --------------------------
// 256x256 tile, BK=64, 512 threads = 8 waves (2M x 4N), per-wave 128x64 output.
// LDS 128 KiB: [2 dbuf][Aklo,Akhi,Bklo,Bkhi][256 rows x 32 k] bf16, 64-B rows.
// Swizzle: 16B chunk within row: phys = logical ^ ((row>>1)&3)  -> 2 lanes/bank (free).
// Staging: one half-tile (2 gll16/thread) issued per phase; waits are s_waitcnt vmcnt(4)
// (counted, never 0 in the main loop) + raw s_barrier.
// Grid flat 512; bid&7 (XCD heuristic) owns 4 whole batches -> P[b]+Etr[b] (4MB) per-XCD L2.
__global__ __launch_bounds__(512, 2) void gemm_k(const us* __restrict__ P,
                                                 const us* __restrict__ Etr,
                                                 const float* __restrict__ rs,
                                                 float* __restrict__ out)
{
  const int bid = blockIdx.x;
  const int xcd = bid & 7;
  const int s   = bid >> 3;             // 0..63
  const int b   = xcd * 4 + (s >> 4);   // 4 batches per XCD
  const int t16 = s & 15;
  const int i0  = (t16 >> 2) * 256;
  const int n0  = (t16 & 3) * 256;

  const int tid  = threadIdx.x;
  const int wid  = tid >> 6;
  const int lane = tid & 63;
  const int wm = wid >> 2, wn = wid & 3;   // 2 x 4 wave grid
  const int ml = lane & 15, quad = lane >> 4;

  __shared__ __align__(16) us lds[2][4][8192];  // [buf][Aklo,Akhi,Bklo,Bkhi][256*32]

  // ---- staging source pointers (pre-swizzled global addresses; q=1 = +128 rows) ----
  const us* gsrc[4];
  {
    int p = tid;                    // physical 16B chunk 0..511 (q=0)
    int r = p >> 2;                 // row 0..127
    int c = (p & 3) ^ ((r >> 1) & 3);   // logical chunk at this physical slot
    const us* arow = P   + ((size_t)b * S_ + (i0 + r)) * S_;
    const us* brow = Etr + ((size_t)b * D_ + (n0 + r)) * S_;
    gsrc[0] = arow + c * 8;         // A klo
    gsrc[1] = arow + 32 + c * 8;    // A khi
    gsrc[2] = brow + c * 8;         // B klo
    gsrc[3] = brow + 32 + c * 8;    // B khi
  }
  const int dst0 = wid * 64 * 8;    // wave-uniform us offset; HW adds lane*16B

  // ---- fragment read offsets (swizzled), per-thread constants ----
  int aoff[8], boff[4];
#pragma unroll
  for (int mt = 0; mt < 8; ++mt){
    int r = wm * 128 + mt * 16 + ml;
    aoff[mt] = r * 32 + ((quad ^ ((r >> 1) & 3)) * 8);
  }
#pragma unroll
  for (int nt = 0; nt < 4; ++nt){
    int r = wn * 64 + nt * 16 + ml;
    boff[nt] = r * 32 + ((quad ^ ((r >> 1) & 3)) * 8);
  }

  f4 acc[8][4];
#pragma unroll
  for (int mt = 0; mt < 8; ++mt)
#pragma unroll
    for (int nt = 0; nt < 4; ++nt){
      f4 z = {0.0f, 0.0f, 0.0f, 0.0f};
      acc[mt][nt] = z;
    }

  // issue one half-tile (16 KB, 2 gll16/thread)
  auto STAGE = [&](int buf, int h, int kt){
    const us* g = gsrc[h] + kt * 64;       // kt*64 us = 128 B per K-tile step
    us* l = &lds[buf][h][dst0];
    gll16(g,                 l);           // rows 0..127 of this half
    gll16(g + 128 * S_,      l + 4096);    // rows 128..255 (chunk base +512 chunks)
  };

  // ---- prologue: tile 0, klo then khi; wait klo, keep khi in flight ----
  STAGE(0, 0, 0); STAGE(0, 2, 0);   // klo A,B  (4 loads)
  STAGE(0, 1, 0); STAGE(0, 3, 0);   // khi A,B  (4 loads)
  asm volatile("s_waitcnt vmcnt(4)" ::: "memory");
  __builtin_amdgcn_s_barrier();
  asm volatile("" ::: "memory");

#pragma unroll 1
  for (int kt = 0; kt < 16; ++kt){
    const int buf = kt & 1, nb = buf ^ 1;
    const int ktn = (kt < 15) ? (kt + 1) : 0;   // clamped prefetch keeps vmcnt stream uniform
    const us* A0 = lds[buf][0];
    const us* A1 = lds[buf][1];
    const us* B0 = lds[buf][2];
    const us* B1 = lds[buf][3];
    short8 av[4], av2[4], bv[4];

    // ---- P1: ks=0, mt 0..3 ----
#pragma unroll
    for (int mt = 0; mt < 4; ++mt) av[mt] = *(const short8*)&A0[aoff[mt]];
#pragma unroll
    for (int nt = 0; nt < 4; ++nt) bv[nt] = *(const short8*)&B0[boff[nt]];
    STAGE(nb, 0, ktn);                               // next A-klo
    __builtin_amdgcn_s_setprio(1);
#pragma unroll
    for (int mt = 0; mt < 4; ++mt)
#pragma unroll
      for (int nt = 0; nt < 4; ++nt)
        acc[mt][nt] = __builtin_amdgcn_mfma_f32_16x16x32_bf16(av[mt], bv[nt], acc[mt][nt], 0, 0, 0);
    __builtin_amdgcn_s_setprio(0);

    // ---- P2: ks=0, mt 4..7 ----
#pragma unroll
    for (int mt = 0; mt < 4; ++mt) av2[mt] = *(const short8*)&A0[aoff[4 + mt]];
    STAGE(nb, 2, ktn);                               // next B-klo
    __builtin_amdgcn_s_setprio(1);
#pragma unroll
    for (int mt = 0; mt < 4; ++mt)
#pragma unroll
      for (int nt = 0; nt < 4; ++nt)
        acc[4 + mt][nt] = __builtin_amdgcn_mfma_f32_16x16x32_bf16(av2[mt], bv[nt], acc[4 + mt][nt], 0, 0, 0);
    __builtin_amdgcn_s_setprio(0);

    asm volatile("s_waitcnt vmcnt(4)" ::: "memory"); // this tile's khi has landed
    __builtin_amdgcn_s_barrier();
    asm volatile("" ::: "memory");

    // ---- P3: ks=1, mt 0..3 ----
#pragma unroll
    for (int mt = 0; mt < 4; ++mt) av[mt] = *(const short8*)&A1[aoff[mt]];
#pragma unroll
    for (int nt = 0; nt < 4; ++nt) bv[nt] = *(const short8*)&B1[boff[nt]];
    STAGE(nb, 1, ktn);                               // next A-khi
    __builtin_amdgcn_s_setprio(1);
#pragma unroll
    for (int mt = 0; mt < 4; ++mt)
#pragma unroll
      for (int nt = 0; nt < 4; ++nt)
        acc[mt][nt] = __builtin_amdgcn_mfma_f32_16x16x32_bf16(av[mt], bv[nt], acc[mt][nt], 0, 0, 0);
    __builtin_amdgcn_s_setprio(0);

    // ---- P4: ks=1, mt 4..7 ----
#pragma unroll
    for (int mt = 0; mt < 4; ++mt) av2[mt] = *(const short8*)&A1[aoff[4 + mt]];
    STAGE(nb, 3, ktn);                               // next B-khi
    __builtin_amdgcn_s_setprio(1);
#pragma unroll
    for (int mt = 0; mt < 4; ++mt)
#pragma unroll
      for (int nt = 0; nt < 4; ++nt)
        acc[4 + mt][nt] = __builtin_amdgcn_mfma_f32_16x16x32_bf16(av2[mt], bv[nt], acc[4 + mt][nt], 0, 0, 0);
    __builtin_amdgcn_s_setprio(0);

    asm volatile("s_waitcnt vmcnt(4)" ::: "memory"); // next tile's klo has landed
    __builtin_amdgcn_s_barrier();
    asm volatile("" ::: "memory");
  }
  asm volatile("s_waitcnt vmcnt(0)" ::: "memory");   // drain fake prefetch before endpgm

  // ---- epilogue: C/D layout col=lane&15 (=d), row=quad*4+reg (=i) ----
  const float* rsb = rs + (size_t)b * S_;
#pragma unroll
  for (int mt = 0; mt < 8; ++mt){
#pragma unroll
    for (int reg = 0; reg < 4; ++reg){
      int i = i0 + wm * 128 + mt * 16 + quad * 4 + reg;
      float rv = rsb[i];
      size_t ob = ((size_t)i * B_ + b) * D_;
#pragma unroll
      for (int nt = 0; nt < 4; ++nt){
        int d = n0 + wn * 64 + nt * 16 + ml;
        out[ob + d] = acc[mt][nt][reg] * rv;
      }
    }
  }
}

// ---------------- fallback kernels (tiny workspace) ----------------------------------------
__device__ __forceinline__ void rowk_body(int blk, const float* __restrict__ x,
                                          const float* __restrict__ Wp,
                                          const float* __restrict__ bp,
                                          const float* __restrict__ valid,
                                          const float* __restrict__ slen,
                                          const float* __restrict__ ltok,
                                          float* __restrict__ rs,
                                          float* __restrict__ c_arr)
{
  const int wid  = threadIdx.x >> 6;
  const int lane = threadIdx.x & 63;
  const int row  = blk * 4 + wid;
  const int b = row & (B_ - 1);
  const int i = row >> 5;

  const float4* xr = (const float4*)(x + (size_t)row * D_);
  const float4* wr = (const float4*)Wp;
  float acc = 0.f;
#pragma unroll
  for (int q = 0; q < 4; ++q){
    float4 xv = xr[q * 64 + lane];
    float4 wv = wr[q * 64 + lane];
    acc += xv.x * wv.x + xv.y * wv.y + xv.z * wv.z + xv.w * wv.w;
  }
#pragma unroll
  for (int off = 32; off > 0; off >>= 1) acc += __shfl_xor(acc, off);

  float z   = acc + bp[0];
  float sig = 1.f / (1.f + expf(-z));
  float c   = sig * slen[b] + ltok[b];

  const float4* vr = (const float4*)(valid + (size_t)b * S_);
  float wsum = 0.f;
#pragma unroll
  for (int q = 0; q < 4; ++q){
    int idx = q * 64 + lane;
    float4 vv = vr[idx];
    float j0 = (float)(idx * 4);
    float d0 = c - j0;
    float d1 = c - (j0 + 1.f);
    float d2 = c - (j0 + 2.f);
    float d3 = c - (j0 + 3.f);
    us p0 = f2bf(vv.x / (d0 * d0 + 1e-3f));
    us p1 = f2bf(vv.y / (d1 * d1 + 1e-3f));
    us p2 = f2bf(vv.z / (d2 * d2 + 1e-3f));
    us p3 = f2bf(vv.w / (d3 * d3 + 1e-3f));
    wsum += bf2f(p0) + bf2f(p1) + bf2f(p2) + bf2f(p3);
  }
#pragma unroll
  for (int off = 32; off > 0; off >>= 1) wsum += __shfl_xor(wsum, off);

  if (lane == 0){
    float vi = valid[(size_t)b * S_ + i];
    rs[(size_t)b * S_ + i] = (vi != 0.f) ? (vi / wsum) : 0.f;
    c_arr[(size_t)b * S_ + i] = c;
  }
}

__global__ __launch_bounds__(256) void rowk_nb(const float* __restrict__ x,
                                               const float* __restrict__ Wp,
                                               const float* __restrict__ bp,
                                               const float* __restrict__ valid,
                                               const float* __restrict__ slen,
                                               const float* __restrict__ ltok,
                                               float* __restrict__ rs,
                                               float* __restrict__ c_arr)
{
  rowk_body(blockIdx.x, x, Wp, bp, valid, slen, ltok, rs, c_arr);
}

__global__ __launch_bounds__(256) void slow_out_k(const float* __restrict__ pe,
                                                  const float* __restrict__ valid,
                                                  const float* __restrict__ c_arr,
                                                  const float* __restrict__ rs,
                                                  float* __restrict__ out)
{
  const int bid = blockIdx.x;
  const int b = bid & (B_ - 1);
  const int i = bid >> 5;
  const int t = threadIdx.x;
  __shared__ float sw[S_];
  float c  = c_arr[(size_t)b * S_ + i];
  float rv = rs[(size_t)b * S_ + i];
#pragma unroll
  for (int q = 0; q < 4; ++q){
    int j = t + q * 256;
    float d = c - (float)j;
    sw[j] = valid[(size_t)b * S_ + j] / (d * d + 1e-3f);
  }
  __syncthreads();
  float a0 = 0, a1 = 0, a2 = 0, a3 = 0;
  if (rv != 0.0f){
    for (int j = 0; j < S_; ++j){
      float wj = sw[j];
      const float* row = pe + ((size_t)j * B_ + b) * D_;
      a0 += wj * row[t];
      a1 += wj * row[t + 256];
      a2 += wj * row[t + 512];
      a3 += wj * row[t + 768];
    }
  }
  float* orow = out + ((size_t)i * B_ + b) * D_;
  orow[t]       = a0 * rv;
  orow[t + 256] = a1 * rv;
  orow[t + 512] = a2 * rv;
  orow[t + 768] = a3 * rv;
}

extern "C" void kernel_launch(void* const* d_in, const int* in_sizes, int n_in,
                              void* d_out, int out_size, void* d_ws, size_t ws_size,
                              hipStream_t stream)
{
  (void)in_sizes; (void)n_in; (void)out_size;
  const float* x  = (const float*)d_in[0];
  // d_in[1] (layer_input) is unused by the reference
  const float* pe = (const float*)d_in[2];
  const unsigned char* mask = (const unsigned char*)d_in[3];
  const float* Wp = (const float*)d_in[4];
  const float* bp = (const float*)d_in[5];
  float* out = (float*)d_out;
  char* ws = (char*)d_ws;

  const size_t offValid = 0;
  const size_t offRs    = offValid + (size_t)B_ * S_ * 4;
  const size_t offSlen  = offRs    + (size_t)B_ * S_ * 4;
  const size_t offLtok  = offSlen  + 128;
  const size_t offC     = offLtok  + 128;
  const size_t offP     = offC     + (size_t)B_ * S_ * 4;
  const size_t offE     = offP     + (size_t)B_ * S_ * S_ * 2;
  const size_t need     = offE     + (size_t)B_ * D_ * S_ * 2;

  float* valid = (float*)(ws + offValid);
  float* rs    = (float*)(ws + offRs);
  float* slen  = (float*)(ws + offSlen);
  float* ltok  = (float*)(ws + offLtok);
  float* c_arr = (float*)(ws + offC);
  us* P   = (us*)(ws + offP);
  us* Etr = (us*)(ws + offE);

  prep_k<<<B_, 256, 0, stream>>>(mask, valid, slen, ltok);
  if (ws_size >= need){
    mid_k<<<8192, 256, 0, stream>>>(x, Wp, bp, valid, slen, ltok, P, rs, c_arr, pe, Etr);
    gemm_k<<<512, 512, 0, stream>>>(P, Etr, rs, out);
  } else {
    rowk_nb<<<S_ * B_ / 4, 256, 0, stream>>>(x, Wp, bp, valid, slen, ltok, rs, c_arr);
    slow_out_k<<<S_ * B_, 256, 0, stream>>>(pe, valid, c_arr, rs, out);
  }
}

// Round 5
// 454.525 us; speedup vs baseline: 1.0390x; 1.0390x over previous
//
#include <hip/hip_runtime.h>

// Problem: S=1024, B=32, D=1024.  All float tensors FP32; output FP32.
// out[i,b,:] = valid[b,i]/denom[i,b] * sum_j w[i,b,j] * PE[j,b,:]
//   w[i,b,j] = valid[b,j] / ((c_ib - j)^2 + 1e-3),  c_ib = sigmoid(x[i,b]·W+b0)*slen_b + (S-slen_b)
// Pipeline: prep (mask->valid/slen) -> mid (R1-measured version: rowk blocks [0,8192) +
//           transpose blocks [8192,16384), v1 64x64 transpose) -> batched bf16 MFMA GEMM.
// GEMM v4: 256x256 tile, BK=32, 8 waves (2Mx4N), DEPTH-2 prefetch via 4 LDS slots
//          (4 x 32 KiB = 128 KiB total, fits the 160 KiB limit that killed v3's 3x64KiB).
//          8 loads always in flight; counted s_waitcnt vmcnt(8), never 0 in the main loop.
// Denominator sums the bf16-ROUNDED weights so P-quantization error cancels in normalization.

#define S_ 1024
#define B_ 32
#define D_ 1024

typedef unsigned short us;
typedef __attribute__((ext_vector_type(4))) unsigned short us4;
typedef __attribute__((ext_vector_type(4))) float f4;
typedef __attribute__((ext_vector_type(8))) short short8;

__device__ __forceinline__ float bf2f(us u){
  unsigned v = ((unsigned)u) << 16;
  float f;
  __builtin_memcpy(&f, &v, 4);
  return f;
}
__device__ __forceinline__ us f2bf(float f){
  unsigned v;
  __builtin_memcpy(&v, &f, 4);
  v = v + 0x7fffu + ((v >> 16) & 1u);   // RNE
  return (us)(v >> 16);
}

// async global->LDS, 16B per lane; lds ptr must be wave-uniform (dest = base + lane*16)
__device__ __forceinline__ void gll16(const void* g, void* l){
  __builtin_amdgcn_global_load_lds(
      (const __attribute__((address_space(1))) void*)g,
      (__attribute__((address_space(3))) void*)l,
      16, 0, 0);
}

// ---------------- kernel 1: mask -> valid_f, slen, ltok (bool storage autodetect) ----------
__global__ __launch_bounds__(256) void prep_k(const unsigned char* __restrict__ mask,
                                              float* __restrict__ valid,
                                              float* __restrict__ slen,
                                              float* __restrict__ ltok)
{
  const int b = blockIdx.x;
  const int t = threadIdx.x;
  __shared__ int flags[5];   // nonzero seen at byte%4==0..3, [4]=any byte>1
  __shared__ int red[256];
  if (t < 5) flags[t] = 0;
  __syncthreads();
  for (int k = 0; k < 32; ++k){
    int p = t * 32 + k;
    unsigned v = mask[p];
    if (v){
      atomicOr(&flags[p & 3], 1);
      if (v > 1u) atomicOr(&flags[4], 1);
    }
  }
  __syncthreads();
  int fmt;  // 0=u8, 1=i32, 2=bf16, 3=f32
  int any123 = flags[1] | flags[2] | flags[3];
  if (!flags[4]) fmt = any123 ? 0 : 1;
  else           fmt = (flags[0] | flags[1]) ? 2 : 3;

  int cnt = 0;
#pragma unroll
  for (int q = 0; q < 4; ++q){
    int j = t + q * 256;
    size_t idx = (size_t)b * S_ + j;
    unsigned mv;
    if (fmt == 0)      mv = mask[idx];
    else if (fmt == 1) mv = ((const unsigned int*)mask)[idx];
    else if (fmt == 2) mv = ((const unsigned short*)mask)[idx];
    else               mv = ((const unsigned int*)mask)[idx] & 0x7fffffffu;
    valid[idx] = mv ? 0.0f : 1.0f;
    cnt += mv ? 0 : 1;
  }
  red[t] = cnt;
  __syncthreads();
  for (int s = 128; s > 0; s >>= 1){
    if (t < s) red[t] += red[t + s];
    __syncthreads();
  }
  if (t == 0){
    float cn = (float)red[0];
    slen[b] = cn;
    ltok[b] = (float)S_ - cn;
  }
}

// ---------------- wave-per-row P builder (no barriers) -------------------------------------
__device__ __forceinline__ void rowk_body(int blk, const float* __restrict__ x,
                                          const float* __restrict__ Wp,
                                          const float* __restrict__ bp,
                                          const float* __restrict__ valid,
                                          const float* __restrict__ slen,
                                          const float* __restrict__ ltok,
                                          us* __restrict__ P,
                                          float* __restrict__ rs,
                                          float* __restrict__ c_arr,
                                          bool writeP)
{
  const int wid  = threadIdx.x >> 6;
  const int lane = threadIdx.x & 63;
  const int row  = blk * 4 + wid;      // row = i*B + b (x layout)
  const int b = row & (B_ - 1);
  const int i = row >> 5;

  const float4* xr = (const float4*)(x + (size_t)row * D_);
  const float4* wr = (const float4*)Wp;
  float acc = 0.f;
#pragma unroll
  for (int q = 0; q < 4; ++q){
    float4 xv = xr[q * 64 + lane];
    float4 wv = wr[q * 64 + lane];
    acc += xv.x * wv.x + xv.y * wv.y + xv.z * wv.z + xv.w * wv.w;
  }
#pragma unroll
  for (int off = 32; off > 0; off >>= 1) acc += __shfl_xor(acc, off);

  float z   = acc + bp[0];
  float sig = 1.f / (1.f + expf(-z));
  float c   = sig * slen[b] + ltok[b];

  const float4* vr = (const float4*)(valid + (size_t)b * S_);
  us4* Pr = (us4*)(P + ((size_t)b * S_ + i) * S_);
  float wsum = 0.f;
#pragma unroll
  for (int q = 0; q < 4; ++q){
    int idx = q * 64 + lane;
    float4 vv = vr[idx];
    float j0 = (float)(idx * 4);
    float d0 = c - j0;
    float d1 = c - (j0 + 1.f);
    float d2 = c - (j0 + 2.f);
    float d3 = c - (j0 + 3.f);
    us p0 = f2bf(vv.x / (d0 * d0 + 1e-3f));
    us p1 = f2bf(vv.y / (d1 * d1 + 1e-3f));
    us p2 = f2bf(vv.z / (d2 * d2 + 1e-3f));
    us p3 = f2bf(vv.w / (d3 * d3 + 1e-3f));
    if (writeP){
      us4 pv; pv.x = p0; pv.y = p1; pv.z = p2; pv.w = p3;
      Pr[idx] = pv;
    }
    wsum += bf2f(p0) + bf2f(p1) + bf2f(p2) + bf2f(p3);
  }
#pragma unroll
  for (int off = 32; off > 0; off >>= 1) wsum += __shfl_xor(wsum, off);

  if (lane == 0){
    float vi = valid[(size_t)b * S_ + i];
    rs[(size_t)b * S_ + i] = (vi != 0.f) ? (vi / wsum) : 0.f;
    c_arr[(size_t)b * S_ + i] = c;
  }
}

// ---------------- PE f32 (S,B,D) -> Etr bf16 (B,D,S), 64x64 tile ---------------------------
__device__ __forceinline__ void transp_body(int j0, int d0, int b,
                                            const float* __restrict__ pe,
                                            us* __restrict__ Etr,
                                            us* tile /* 64*68 us */)
{
  const int t  = threadIdx.x;
  const int rr = t >> 4, cc = t & 15;
#pragma unroll
  for (int q = 0; q < 4; ++q){
    int j = q * 16 + rr;
    float4 v = *(const float4*)(pe + ((size_t)(j0 + j) * B_ + b) * D_ + d0 + cc * 4);
    us4 tv; tv.x = f2bf(v.x); tv.y = f2bf(v.y); tv.z = f2bf(v.z); tv.w = f2bf(v.w);
    *(us4*)&tile[j * 68 + cc * 4] = tv;
  }
  __syncthreads();
#pragma unroll
  for (int q = 0; q < 4; ++q){
    int d = q * 16 + rr;
    us4 v;
    v.x = tile[(cc * 4 + 0) * 68 + d];
    v.y = tile[(cc * 4 + 1) * 68 + d];
    v.z = tile[(cc * 4 + 2) * 68 + d];
    v.w = tile[(cc * 4 + 3) * 68 + d];
    *(us4*)(Etr + ((size_t)b * D_ + d0 + d) * S_ + j0 + cc * 4) = v;
  }
}

// ---------------- kernel 2 (FUSED): rowk blocks [0,8192) + transpose blocks [8192,16384) ---
__global__ __launch_bounds__(256) void mid_k(const float* __restrict__ x,
                                             const float* __restrict__ Wp,
                                             const float* __restrict__ bp,
                                             const float* __restrict__ valid,
                                             const float* __restrict__ slen,
                                             const float* __restrict__ ltok,
                                             us* __restrict__ P,
                                             float* __restrict__ rs,
                                             float* __restrict__ c_arr,
                                             const float* __restrict__ pe,
                                             us* __restrict__ Etr)
{
  __shared__ us tile[64 * 68];
  const int bid = blockIdx.x;
  if (bid < (S_ * B_ / 4)){
    rowk_body(bid, x, Wp, bp, valid, slen, ltok, P, rs, c_arr, true);
  } else {
    int id2 = bid - (S_ * B_ / 4);
    int jt = id2 & 15;
    int dt = (id2 >> 4) & 15;
    int b  = id2 >> 8;
    transp_body(jt * 64, dt * 64, b, pe, Etr, tile);
  }
}

// ---------------- kernel 3: batched GEMM out = rowscale * (P @ E) --------------------------
// v4: 256x256 tile, BK=32, 512 threads = 8 waves (2M x 4N), per-wave 128x64 output.
// LDS 128 KiB: [4 slots][A,B][256 rows x 32 k] bf16, 64-B rows (4 x 16B chunks).
// Swizzle: 16B chunk within row: phys = logical ^ ((row>>1)&3)  -> 2 lanes/bank (free).
// DEPTH-2 prefetch: iter kt computes slot kt&3, stages K-step kt+3 into slot (kt+3)&3
//   (= slot of step kt-1, whose reads were consumed by kt-1's MFMAs before its end barrier).
// Loads: 4 gll16 per K-step (A lo-rows, A hi-rows, B lo, B hi).
// Invariant entering kt: outstanding = steps kt+1, kt+2 = 8 loads.
//   during kt: +4 issued (16 total in flight never exceeded) -> end vmcnt(8) drains exactly
//   step kt+1 (what the next iter reads); single barrier per K-step.
// Tail (kt>=29): clamped re-stage of step 31 into dead slots; final vmcnt(0) before epilogue.
// Grid flat 512; bid&7 (XCD heuristic) owns 4 whole batches -> P[b]+Etr[b] (4MB) per-XCD L2.
__global__ __launch_bounds__(512, 2) void gemm_k(const us* __restrict__ P,
                                                 const us* __restrict__ Etr,
                                                 const float* __restrict__ rs,
                                                 float* __restrict__ out)
{
  const int bid = blockIdx.x;
  const int xcd = bid & 7;
  const int s   = bid >> 3;             // 0..63
  const int b   = xcd * 4 + (s >> 4);   // 4 batches per XCD
  const int t16 = s & 15;
  const int i0  = (t16 >> 2) * 256;
  const int n0  = (t16 & 3) * 256;

  const int tid  = threadIdx.x;
  const int wid  = tid >> 6;
  const int lane = tid & 63;
  const int wm = wid >> 2, wn = wid & 3;   // 2 x 4 wave grid
  const int ml = lane & 15, quad = lane >> 4;

  __shared__ __align__(16) us lds[4][2][8192];  // 128 KiB: [slot][A,B][256*32]

  // ---- staging source pointers (pre-swizzled global addresses) ----
  const us* gsrc[2];
  {
    int p = tid;                    // physical 16B chunk 0..511 (rows 0..127)
    int r = p >> 2;                 // row 0..127
    int c = (p & 3) ^ ((r >> 1) & 3);   // logical column chunk at this physical slot
    gsrc[0] = P   + ((size_t)b * S_ + (i0 + r)) * S_ + c * 8;
    gsrc[1] = Etr + ((size_t)b * D_ + (n0 + r)) * S_ + c * 8;
  }
  const int dst0 = wid * 64 * 8;    // wave-uniform us offset; HW adds lane*16B

  // ---- fragment read offsets (swizzled), per-thread constants ----
  int aoff[8], boff[4];
#pragma unroll
  for (int mt = 0; mt < 8; ++mt){
    int r = wm * 128 + mt * 16 + ml;
    aoff[mt] = r * 32 + ((quad ^ ((r >> 1) & 3)) * 8);
  }
#pragma unroll
  for (int nt = 0; nt < 4; ++nt){
    int r = wn * 64 + nt * 16 + ml;
    boff[nt] = r * 32 + ((quad ^ ((r >> 1) & 3)) * 8);
  }

  f4 acc[8][4];
#pragma unroll
  for (int mt = 0; mt < 8; ++mt)
#pragma unroll
    for (int nt = 0; nt < 4; ++nt){
      f4 z = {0.0f, 0.0f, 0.0f, 0.0f};
      acc[mt][nt] = z;
    }

  // stage one matrix-half of one K-step (16 KB, 2 gll16/thread)
  auto STAGE = [&](int slot, int h, int kt){
    const us* g = gsrc[h] + kt * 32;       // kt*32 us = 64 B per K-step
    us* l = &lds[slot][h][dst0];
    gll16(g,                 l);           // rows 0..127
    gll16(g + 128 * S_,      l + 4096);    // rows 128..255
  };

  // ---- prologue: steps 0,1,2 fully issued (12 loads); wait step 0, keep 8 in flight ----
  STAGE(0, 0, 0); STAGE(0, 1, 0);
  STAGE(1, 0, 1); STAGE(1, 1, 1);
  STAGE(2, 0, 2); STAGE(2, 1, 2);
  asm volatile("s_waitcnt vmcnt(8)" ::: "memory");   // step 0 (oldest 4) landed
  __builtin_amdgcn_s_barrier();
  asm volatile("" ::: "memory");

#pragma unroll 1
  for (int kt = 0; kt < 32; ++kt){
    const int sl  = kt & 3;
    const int st  = (kt + 3) & 3;
    const int ktn = (kt < 29) ? (kt + 3) : 31;   // clamped tail keeps vmcnt stream uniform
    const us* A = lds[sl][0];
    const us* B = lds[sl][1];
    short8 av[4], av2[4], bv[4];

    // ---- P1: mt 0..3 ----
#pragma unroll
    for (int mt = 0; mt < 4; ++mt) av[mt] = *(const short8*)&A[aoff[mt]];
#pragma unroll
    for (int nt = 0; nt < 4; ++nt) bv[nt] = *(const short8*)&B[boff[nt]];
    STAGE(st, 0, ktn);                               // A(kt+3)
    __builtin_amdgcn_s_setprio(1);
#pragma unroll
    for (int mt = 0; mt < 4; ++mt)
#pragma unroll
      for (int nt = 0; nt < 4; ++nt)
        acc[mt][nt] = __builtin_amdgcn_mfma_f32_16x16x32_bf16(av[mt], bv[nt], acc[mt][nt], 0, 0, 0);
    __builtin_amdgcn_s_setprio(0);

    // ---- P2: mt 4..7 ----
#pragma unroll
    for (int mt = 0; mt < 4; ++mt) av2[mt] = *(const short8*)&A[aoff[4 + mt]];
    STAGE(st, 1, ktn);                               // B(kt+3)
    __builtin_amdgcn_s_setprio(1);
#pragma unroll
    for (int mt = 0; mt < 4; ++mt)
#pragma unroll
      for (int nt = 0; nt < 4; ++nt)
        acc[4 + mt][nt] = __builtin_amdgcn_mfma_f32_16x16x32_bf16(av2[mt], bv[nt], acc[4 + mt][nt], 0, 0, 0);
    __builtin_amdgcn_s_setprio(0);

    asm volatile("s_waitcnt vmcnt(8)" ::: "memory"); // step kt+1 landed (oldest 4 of 12)
    __builtin_amdgcn_s_barrier();
    asm volatile("" ::: "memory");
  }
  asm volatile("s_waitcnt vmcnt(0)" ::: "memory");   // drain clamped tail before epilogue

  // ---- epilogue: C/D layout col=lane&15 (=d), row=quad*4+reg (=i) ----
  const float* rsb = rs + (size_t)b * S_;
#pragma unroll
  for (int mt = 0; mt < 8; ++mt){
#pragma unroll
    for (int reg = 0; reg < 4; ++reg){
      int i = i0 + wm * 128 + mt * 16 + quad * 4 + reg;
      float rv = rsb[i];
      size_t ob = ((size_t)i * B_ + b) * D_;
#pragma unroll
      for (int nt = 0; nt < 4; ++nt){
        int d = n0 + wn * 64 + nt * 16 + ml;
        out[ob + d] = acc[mt][nt][reg] * rv;
      }
    }
  }
}

// ---------------- fallback kernels (tiny workspace) ----------------------------------------
__global__ __launch_bounds__(256) void rowk_nb(const float* __restrict__ x,
                                               const float* __restrict__ Wp,
                                               const float* __restrict__ bp,
                                               const float* __restrict__ valid,
                                               const float* __restrict__ slen,
                                               const float* __restrict__ ltok,
                                               float* __restrict__ rs,
                                               float* __restrict__ c_arr)
{
  rowk_body(blockIdx.x, x, Wp, bp, valid, slen, ltok, nullptr, rs, c_arr, false);
}

__global__ __launch_bounds__(256) void slow_out_k(const float* __restrict__ pe,
                                                  const float* __restrict__ valid,
                                                  const float* __restrict__ c_arr,
                                                  const float* __restrict__ rs,
                                                  float* __restrict__ out)
{
  const int bid = blockIdx.x;
  const int b = bid & (B_ - 1);
  const int i = bid >> 5;
  const int t = threadIdx.x;
  __shared__ float sw[S_];
  float c  = c_arr[(size_t)b * S_ + i];
  float rv = rs[(size_t)b * S_ + i];
#pragma unroll
  for (int q = 0; q < 4; ++q){
    int j = t + q * 256;
    float d = c - (float)j;
    sw[j] = valid[(size_t)b * S_ + j] / (d * d + 1e-3f);
  }
  __syncthreads();
  float a0 = 0, a1 = 0, a2 = 0, a3 = 0;
  if (rv != 0.0f){
    for (int j = 0; j < S_; ++j){
      float wj = sw[j];
      const float* row = pe + ((size_t)j * B_ + b) * D_;
      a0 += wj * row[t];
      a1 += wj * row[t + 256];
      a2 += wj * row[t + 512];
      a3 += wj * row[t + 768];
    }
  }
  float* orow = out + ((size_t)i * B_ + b) * D_;
  orow[t]       = a0 * rv;
  orow[t + 256] = a1 * rv;
  orow[t + 512] = a2 * rv;
  orow[t + 768] = a3 * rv;
}

extern "C" void kernel_launch(void* const* d_in, const int* in_sizes, int n_in,
                              void* d_out, int out_size, void* d_ws, size_t ws_size,
                              hipStream_t stream)
{
  (void)in_sizes; (void)n_in; (void)out_size;
  const float* x  = (const float*)d_in[0];
  // d_in[1] (layer_input) is unused by the reference
  const float* pe = (const float*)d_in[2];
  const unsigned char* mask = (const unsigned char*)d_in[3];
  const float* Wp = (const float*)d_in[4];
  const float* bp = (const float*)d_in[5];
  float* out = (float*)d_out;
  char* ws = (char*)d_ws;

  const size_t offValid = 0;
  const size_t offRs    = offValid + (size_t)B_ * S_ * 4;
  const size_t offSlen  = offRs    + (size_t)B_ * S_ * 4;
  const size_t offLtok  = offSlen  + 128;
  const size_t offC     = offLtok  + 128;
  const size_t offP     = offC     + (size_t)B_ * S_ * 4;
  const size_t offE     = offP     + (size_t)B_ * S_ * S_ * 2;
  const size_t need     = offE     + (size_t)B_ * D_ * S_ * 2;

  float* valid = (float*)(ws + offValid);
  float* rs    = (float*)(ws + offRs);
  float* slen  = (float*)(ws + offSlen);
  float* ltok  = (float*)(ws + offLtok);
  float* c_arr = (float*)(ws + offC);
  us* P   = (us*)(ws + offP);
  us* Etr = (us*)(ws + offE);

  prep_k<<<B_, 256, 0, stream>>>(mask, valid, slen, ltok);
  if (ws_size >= need){
    mid_k<<<16384, 256, 0, stream>>>(x, Wp, bp, valid, slen, ltok, P, rs, c_arr, pe, Etr);
    gemm_k<<<512, 512, 0, stream>>>(P, Etr, rs, out);
  } else {
    rowk_nb<<<S_ * B_ / 4, 256, 0, stream>>>(x, Wp, bp, valid, slen, ltok, rs, c_arr);
    slow_out_k<<<S_ * B_, 256, 0, stream>>>(pe, valid, c_arr, rs, out);
  }
}